// Round 4
// baseline (608.855 us; speedup 1.0000x reference)
//
#include <hip/hip_runtime.h>
#include <hip/hip_bf16.h>

// WanSelfAttention: x[1,3584,1536] -> QKV proj -> RMSNorm(full dim) -> 3D RoPE
// -> 12-head attention (HD=128) -> out proj. All matmuls bf16 MFMA, f32 accum.

#define DIM   1536
#define HEADS 12
#define HD    128
#define LSEQ  3584

typedef __bf16 bf16_t;
typedef __attribute__((ext_vector_type(8))) __bf16 bf16x8;
typedef __attribute__((ext_vector_type(4))) float f32x4;
typedef __attribute__((ext_vector_type(16))) float f32x16;

static __device__ __forceinline__ ushort f2bf(float f) {
  bf16_t h = (bf16_t)f;
  return __builtin_bit_cast(ushort, h);
}
static __device__ __forceinline__ float bf2f(ushort u) {
  return (float)__builtin_bit_cast(bf16_t, u);
}
static __device__ __forceinline__ uint pkbf(float a, float b) {
  return (uint)f2bf(a) | ((uint)f2bf(b) << 16);
}

// ---------------- f32 -> bf16 convert ----------------
__global__ __launch_bounds__(256) void cvt_f32_bf16(const float* __restrict__ in,
                                                    ushort* __restrict__ out, int n) {
  int i = (blockIdx.x * 256 + threadIdx.x) * 4;
  if (i + 3 < n) {
    float4 v = *reinterpret_cast<const float4*>(in + i);
    ushort4 o;
    o.x = f2bf(v.x); o.y = f2bf(v.y); o.z = f2bf(v.z); o.w = f2bf(v.w);
    *reinterpret_cast<ushort4*>(out + i) = o;
  }
}

// ---------------- GEMM: C[M][N] = A[M][K] @ B[N][K]^T + bias ----------------
template <bool OUT_F32>
__global__ __launch_bounds__(256) void gemm_bt(const ushort* __restrict__ A,
                                               const ushort* __restrict__ B,
                                               const float* __restrict__ bias,
                                               void* __restrict__ Cout,
                                               int M, int N, int K) {
  __shared__ __attribute__((aligned(16))) ushort As[128 * 32];
  __shared__ __attribute__((aligned(16))) ushort Bs[128 * 32];
  const int tid  = threadIdx.x;
  const int lane = tid & 63;
  const int wid  = tid >> 6;
  const int m0 = blockIdx.x * 128;
  const int n0 = blockIdx.y * 128;
  const int wm = (wid >> 1) * 64;
  const int wn = (wid & 1) * 64;
  const int lr = lane & 15;
  const int lg = lane >> 4;
  const int crow = lane >> 2;
  const int ccol = (lane & 3) * 8;

  f32x4 acc[4][4] = {};

  for (int kt = 0; kt < K; kt += 32) {
    __syncthreads();
#pragma unroll
    for (int i = 0; i < 2; ++i) {
      int chunk = wid * 2 + i;
      int row = chunk * 16 + crow;
      const ushort* ga = A + (size_t)(m0 + row) * K + kt + ccol;
      const ushort* gb = B + (size_t)(n0 + row) * K + kt + ccol;
      __builtin_amdgcn_global_load_lds(
          (__attribute__((address_space(1))) void*)(void*)ga,
          (__attribute__((address_space(3))) void*)(&As[chunk * 512]), 16, 0, 0);
      __builtin_amdgcn_global_load_lds(
          (__attribute__((address_space(1))) void*)(void*)gb,
          (__attribute__((address_space(3))) void*)(&Bs[chunk * 512]), 16, 0, 0);
    }
    __syncthreads();

    bf16x8 af[4], bf[4];
#pragma unroll
    for (int m = 0; m < 4; ++m)
      af[m] = *reinterpret_cast<const bf16x8*>(&As[(wm + m * 16 + lr) * 32 + lg * 8]);
#pragma unroll
    for (int n = 0; n < 4; ++n)
      bf[n] = *reinterpret_cast<const bf16x8*>(&Bs[(wn + n * 16 + lr) * 32 + lg * 8]);
#pragma unroll
    for (int m = 0; m < 4; ++m)
#pragma unroll
      for (int n = 0; n < 4; ++n)
        acc[m][n] = __builtin_amdgcn_mfma_f32_16x16x32_bf16(af[m], bf[n], acc[m][n], 0, 0, 0);
  }

#pragma unroll
  for (int m = 0; m < 4; ++m) {
#pragma unroll
    for (int n = 0; n < 4; ++n) {
      int col = n0 + wn + n * 16 + lr;
      float bv = bias[col];
#pragma unroll
      for (int r = 0; r < 4; ++r) {
        int row = m0 + wm + m * 16 + lg * 4 + r;
        float v = acc[m][n][r] + bv;
        if (OUT_F32)
          ((float*)Cout)[(size_t)row * N + col] = v;
        else
          ((ushort*)Cout)[(size_t)row * N + col] = f2bf(v);
      }
    }
  }
}

// ---------------- RMSNorm(full 1536) + 3D RoPE, in place on bf16 ----------------
__global__ __launch_bounds__(256) void normrope(ushort* __restrict__ Qb,
                                                ushort* __restrict__ Kb,
                                                const float* __restrict__ gq,
                                                const float* __restrict__ gk,
                                                const float* __restrict__ cosT,
                                                const float* __restrict__ sinT) {
  __shared__ float red[4];
  const int l = blockIdx.x;
  const int tid = threadIdx.x;
  ushort* row = (blockIdx.y == 0 ? Qb : Kb) + (size_t)l * DIM;
  const float* g = blockIdx.y == 0 ? gq : gk;

  const uint* rp = reinterpret_cast<const uint*>(row);
  uint pk[3];
  float v[6];
#pragma unroll
  for (int i = 0; i < 3; ++i) {
    pk[i] = rp[tid * 3 + i];
    v[2 * i]     = bf2f((ushort)(pk[i] & 0xffff));
    v[2 * i + 1] = bf2f((ushort)(pk[i] >> 16));
  }
  float ss = 0.f;
#pragma unroll
  for (int i = 0; i < 6; ++i) ss += v[i] * v[i];
#pragma unroll
  for (int off = 1; off < 64; off <<= 1) ss += __shfl_xor(ss, off, 64);
  if ((tid & 63) == 0) red[tid >> 6] = ss;
  __syncthreads();
  float tot = red[0] + red[1] + red[2] + red[3];
  float rms = rsqrtf(tot * (1.0f / DIM) + 1e-6f);

  const int fi = l / 448;
  const int rem = l % 448;
  const int hi = rem / 28;
  const int wi = rem % 28;

  uint* wp = reinterpret_cast<uint*>(row);
#pragma unroll
  for (int i = 0; i < 3; ++i) {
    int p = tid * 3 + i;
    int head = p >> 6;
    int j = p & 63;
    int trow = (j < 22) ? fi : ((j < 43) ? hi : wi);
    float cv = cosT[trow * 64 + j];
    float sv = sinT[trow * 64 + j];
    int idx = head * 128 + 2 * j;
    float xr = v[2 * i] * rms * g[idx];
    float xi = v[2 * i + 1] * rms * g[idx + 1];
    float orr = xr * cv - xi * sv;
    float oii = xr * sv + xi * cv;
    wp[p] = (uint)f2bf(orr) | ((uint)f2bf(oii) << 16);
  }
}

// ---------------- flash attention v2: 4 waves x 32 q-rows, KVB=64, 32x32 MFMA ----
// Swapped QK^T: S^T = mfma(K_frag, Q_frag) -> col=lane&31=q, row=crow(r,hi)=k.
// Softmax fully per-lane (+1 shfl_xor(32)); P via per-wave LDS; V^T staged in LDS.
#define QBLK 128
#define KVB  64

__global__ __launch_bounds__(256) void attn(const ushort* __restrict__ Q,
                                            const ushort* __restrict__ Kp,
                                            const ushort* __restrict__ Vp,
                                            ushort* __restrict__ O) {
  // Ks: linear [64][128] ushort, content XOR-swizzled: byte b of row r holds
  // K[r][(b ^ ((r&7)<<4))/2]  (staged via pre-swizzled global_load_lds source)
  __shared__ __attribute__((aligned(16))) ushort Ks[KVB * 128];
  __shared__ __attribute__((aligned(16))) ushort Vt[128][72];   // V^T [d][k], padded
  __shared__ __attribute__((aligned(16))) ushort Ps[4][32][72]; // per-wave P [q][k=0..63], padded
  const int tid  = threadIdx.x;
  const int lane = tid & 63;
  const int wv   = tid >> 6;
  const int lq   = lane & 31;
  const int hi   = lane >> 5;
  const int h    = blockIdx.y;
  const int q0   = blockIdx.x * QBLK;
  const float scale = 0.08838834764831845f; // 1/sqrt(128)

  // Q fragments (B-operand): lane holds Q[q=lq][d = dstep*16 + hi*8 + j]
  bf16x8 qf[8];
  {
    const ushort* qbase = Q + (size_t)(q0 + wv * 32 + lq) * DIM + h * HD;
#pragma unroll
    for (int d = 0; d < 8; ++d)
      qf[d] = *reinterpret_cast<const bf16x8*>(qbase + d * 16 + hi * 8);
  }

  f32x16 accO[4] = {}; // [nd]: col d = nd*32+lq, row q = crow(r,hi)
  float m = -1e30f, lsum = 0.f;

  const int mbk = tid >> 4;  // 0..15 -> kv rows [4*mbk, +4)
  const int mbd = tid & 15;  // 0..15 -> d cols  [8*mbd, +8)

  for (int kv0 = 0; kv0 < LSEQ; kv0 += KVB) {
    __syncthreads();
    // ---- K stage: swizzled source -> linear LDS, 4 issues/wave ----
#pragma unroll
    for (int i = 0; i < 4; ++i) {
      int o16 = (wv * 4 + i) * 64 + lane;        // 16B-unit index in tile
      int r = o16 >> 4;
      int b = (o16 & 15) * 16;                   // byte col within row
      int srcu = (b ^ ((r & 7) << 4)) >> 1;      // pre-swizzled ushort col
      const ushort* gp = Kp + (size_t)(kv0 + r) * DIM + h * HD + srcu;
      __builtin_amdgcn_global_load_lds(
          (__attribute__((address_space(1))) void*)(void*)gp,
          (__attribute__((address_space(3))) void*)(&Ks[(wv * 4 + i) * 512]), 16, 0, 0);
    }
    // ---- V stage: 4x8 micro-block transpose, b64 writes (bank-rotated) ----
    {
      const ushort* vbase = Vp + (size_t)(kv0 + mbk * 4) * DIM + h * HD + mbd * 8;
      uint4 r0 = *reinterpret_cast<const uint4*>(vbase);
      uint4 r1 = *reinterpret_cast<const uint4*>(vbase + DIM);
      uint4 r2 = *reinterpret_cast<const uint4*>(vbase + 2 * DIM);
      uint4 r3 = *reinterpret_cast<const uint4*>(vbase + 3 * DIM);
      const ushort* s0 = reinterpret_cast<const ushort*>(&r0);
      const ushort* s1 = reinterpret_cast<const ushort*>(&r1);
      const ushort* s2 = reinterpret_cast<const ushort*>(&r2);
      const ushort* s3 = reinterpret_cast<const ushort*>(&r3);
#pragma unroll
      for (int jj = 0; jj < 8; ++jj) {
        int j = (jj + mbd) & 7;  // rotate write order to spread banks
        uint2 w;
        w.x = (uint)s0[j] | ((uint)s1[j] << 16);
        w.y = (uint)s2[j] | ((uint)s3[j] << 16);
        *reinterpret_cast<uint2*>(&Vt[mbd * 8 + j][mbk * 4]) = w;
      }
    }
    __syncthreads();

    // ---- QK^T: S^T[k][q] in two 32-k halves ----
    f32x16 s0v = {}, s1v = {};
#pragma unroll
    for (int d = 0; d < 8; ++d) {
      int db = d * 32 + hi * 16;   // byte col of this lane's 16B A-chunk
      const bf16x8 a0 = *reinterpret_cast<const bf16x8*>(
          (const char*)Ks + lq * 256 + (db ^ ((lq & 7) << 4)));
      s0v = __builtin_amdgcn_mfma_f32_32x32x16_bf16(a0, qf[d], s0v, 0, 0, 0);
      const bf16x8 a1 = *reinterpret_cast<const bf16x8*>(
          (const char*)Ks + (32 + lq) * 256 + (db ^ ((lq & 7) << 4)));
      s1v = __builtin_amdgcn_mfma_f32_32x32x16_bf16(a1, qf[d], s1v, 0, 0, 0);
    }

    // ---- softmax (per-lane over 32 values; partner lane has other 32) ----
    float pmax = s0v[0];
#pragma unroll
    for (int r = 1; r < 16; ++r) pmax = fmaxf(pmax, s0v[r]);
#pragma unroll
    for (int r = 0; r < 16; ++r) pmax = fmaxf(pmax, s1v[r]);
    pmax = fmaxf(pmax, __shfl_xor(pmax, 32, 64));
    pmax *= scale;

    if (__any(pmax > m + 8.f)) {   // defer-max (T13)
      float mn = fmaxf(m, pmax);
      float al = __expf(m - mn);
      m = mn;
      lsum *= al;
#pragma unroll
      for (int r = 0; r < 16; ++r) {
        int qr = (r & 3) + 8 * (r >> 2) + 4 * hi;
        float alr = __shfl(al, qr, 64);
        accO[0][r] *= alr; accO[1][r] *= alr;
        accO[2][r] *= alr; accO[3][r] *= alr;
      }
    }

    float psum = 0.f;
#pragma unroll
    for (int ri = 0; ri < 4; ++ri) {
      // half 0: k = 8*ri + 4*hi + rr
      {
        float p0 = __expf(fmaf(s0v[ri * 4 + 0], scale, -m));
        float p1 = __expf(fmaf(s0v[ri * 4 + 1], scale, -m));
        float p2 = __expf(fmaf(s0v[ri * 4 + 2], scale, -m));
        float p3 = __expf(fmaf(s0v[ri * 4 + 3], scale, -m));
        psum += (p0 + p1) + (p2 + p3);
        uint2 w; w.x = pkbf(p0, p1); w.y = pkbf(p2, p3);
        *reinterpret_cast<uint2*>(&Ps[wv][lq][8 * ri + 4 * hi]) = w;
      }
      // half 1: k = 32 + 8*ri + 4*hi + rr
      {
        float p0 = __expf(fmaf(s1v[ri * 4 + 0], scale, -m));
        float p1 = __expf(fmaf(s1v[ri * 4 + 1], scale, -m));
        float p2 = __expf(fmaf(s1v[ri * 4 + 2], scale, -m));
        float p3 = __expf(fmaf(s1v[ri * 4 + 3], scale, -m));
        psum += (p0 + p1) + (p2 + p3);
        uint2 w; w.x = pkbf(p0, p1); w.y = pkbf(p2, p3);
        *reinterpret_cast<uint2*>(&Ps[wv][lq][32 + 8 * ri + 4 * hi]) = w;
      }
    }
    psum += __shfl_xor(psum, 32, 64);
    lsum += psum;

    // ---- PV: O += P @ V  (A = P from Ps, B = V^T from Vt) ----
#pragma unroll
    for (int ks = 0; ks < 4; ++ks) {
      bf16x8 pa = *reinterpret_cast<const bf16x8*>(&Ps[wv][lq][ks * 16 + hi * 8]);
#pragma unroll
      for (int nd = 0; nd < 4; ++nd) {
        bf16x8 vb = *reinterpret_cast<const bf16x8*>(&Vt[nd * 32 + lq][ks * 16 + hi * 8]);
        accO[nd] = __builtin_amdgcn_mfma_f32_32x32x16_bf16(pa, vb, accO[nd], 0, 0, 0);
      }
    }
  }

  // ---- epilogue ----
  float inv_own = 1.0f / lsum;
#pragma unroll
  for (int r = 0; r < 16; ++r) {
    int qr = (r & 3) + 8 * (r >> 2) + 4 * hi;
    float inv = __shfl(inv_own, qr, 64);
    ushort* orow = O + (size_t)(q0 + wv * 32 + qr) * DIM + h * HD;
#pragma unroll
    for (int nd = 0; nd < 4; ++nd)
      orow[nd * 32 + lq] = f2bf(accO[nd][r] * inv);
  }
}

// ---------------- launch ----------------
extern "C" void kernel_launch(void* const* d_in, const int* in_sizes, int n_in,
                              void* d_out, int out_size, void* d_ws, size_t ws_size,
                              hipStream_t stream) {
  (void)in_sizes; (void)n_in; (void)out_size;
  const float* x    = (const float*)d_in[0];
  const float* cosT = (const float*)d_in[1];
  const float* sinT = (const float*)d_in[2];
  const float* Wq   = (const float*)d_in[3];
  const float* bq   = (const float*)d_in[4];
  const float* Wk   = (const float*)d_in[5];
  const float* bk   = (const float*)d_in[6];
  const float* Wv   = (const float*)d_in[7];
  const float* bv   = (const float*)d_in[8];
  const float* Wo   = (const float*)d_in[9];
  const float* bo   = (const float*)d_in[10];
  const float* gq   = (const float*)d_in[11];
  const float* gk   = (const float*)d_in[12];

  const size_t LD = (size_t)LSEQ * DIM;
  const size_t WD = (size_t)DIM * DIM;
  if (ws_size < (5 * LD + 4 * WD) * sizeof(ushort)) return;

  ushort* xb  = (ushort*)d_ws;
  ushort* Wqb = xb + LD;
  ushort* Wkb = Wqb + WD;
  ushort* Wvb = Wkb + WD;
  ushort* Wob = Wvb + WD;
  ushort* Qb  = Wob + WD;
  ushort* Kb  = Qb + LD;
  ushort* Vb  = Kb + LD;
  ushort* Ob  = Vb + LD;

  cvt_f32_bf16<<<(int)(LD / 4 / 256), 256, 0, stream>>>(x, xb, (int)LD);
  cvt_f32_bf16<<<(int)(WD / 4 / 256), 256, 0, stream>>>(Wq, Wqb, (int)WD);
  cvt_f32_bf16<<<(int)(WD / 4 / 256), 256, 0, stream>>>(Wk, Wkb, (int)WD);
  cvt_f32_bf16<<<(int)(WD / 4 / 256), 256, 0, stream>>>(Wv, Wvb, (int)WD);
  cvt_f32_bf16<<<(int)(WD / 4 / 256), 256, 0, stream>>>(Wo, Wob, (int)WD);

  dim3 ggrid(LSEQ / 128, DIM / 128);
  gemm_bt<false><<<ggrid, 256, 0, stream>>>(xb, Wqb, bq, Qb, LSEQ, DIM, DIM);
  gemm_bt<false><<<ggrid, 256, 0, stream>>>(xb, Wkb, bk, Kb, LSEQ, DIM, DIM);
  gemm_bt<false><<<ggrid, 256, 0, stream>>>(xb, Wvb, bv, Vb, LSEQ, DIM, DIM);

  normrope<<<dim3(LSEQ, 2), 256, 0, stream>>>(Qb, Kb, gq, gk, cosT, sinT);

  attn<<<dim3(LSEQ / QBLK, HEADS), 256, 0, stream>>>(Qb, Kb, Vb, Ob);

  gemm_bt<true><<<ggrid, 256, 0, stream>>>(Ob, Wob, bo, d_out, LSEQ, DIM, DIM);
}

// Round 5
// 497.978 us; speedup vs baseline: 1.2227x; 1.2227x over previous
//
#include <hip/hip_runtime.h>
#include <hip/hip_bf16.h>

// WanSelfAttention: x[1,3584,1536] -> QKV proj -> RMSNorm(full dim) -> 3D RoPE
// -> 12-head attention (HD=128) -> out proj. All matmuls bf16 MFMA, f32 accum.

#define DIM   1536
#define HEADS 12
#define HD    128
#define LSEQ  3584

typedef __bf16 bf16_t;
typedef __attribute__((ext_vector_type(8))) __bf16 bf16x8;
typedef __attribute__((ext_vector_type(4))) float f32x4;
typedef __attribute__((ext_vector_type(16))) float f32x16;

static __device__ __forceinline__ ushort f2bf(float f) {
  bf16_t h = (bf16_t)f;
  return __builtin_bit_cast(ushort, h);
}
static __device__ __forceinline__ float bf2f(ushort u) {
  return (float)__builtin_bit_cast(bf16_t, u);
}
static __device__ __forceinline__ uint pkbf(float a, float b) {
  return (uint)f2bf(a) | ((uint)f2bf(b) << 16);
}

// ---------------- f32 -> bf16 convert ----------------
__global__ __launch_bounds__(256) void cvt_f32_bf16(const float* __restrict__ in,
                                                    ushort* __restrict__ out, int n) {
  int i = (blockIdx.x * 256 + threadIdx.x) * 4;
  if (i + 3 < n) {
    float4 v = *reinterpret_cast<const float4*>(in + i);
    ushort4 o;
    o.x = f2bf(v.x); o.y = f2bf(v.y); o.z = f2bf(v.z); o.w = f2bf(v.w);
    *reinterpret_cast<ushort4*>(out + i) = o;
  }
}

// ---------------- GEMM: C[M][N] = A[M][K] @ B[N][K]^T + bias ----------------
template <bool OUT_F32>
__global__ __launch_bounds__(256) void gemm_bt(const ushort* __restrict__ A,
                                               const ushort* __restrict__ B,
                                               const float* __restrict__ bias,
                                               void* __restrict__ Cout,
                                               int M, int N, int K) {
  __shared__ __attribute__((aligned(16))) ushort As[128 * 32];
  __shared__ __attribute__((aligned(16))) ushort Bs[128 * 32];
  const int tid  = threadIdx.x;
  const int lane = tid & 63;
  const int wid  = tid >> 6;
  const int m0 = blockIdx.x * 128;
  const int n0 = blockIdx.y * 128;
  const int wm = (wid >> 1) * 64;
  const int wn = (wid & 1) * 64;
  const int lr = lane & 15;
  const int lg = lane >> 4;
  const int crow = lane >> 2;
  const int ccol = (lane & 3) * 8;

  f32x4 acc[4][4] = {};

  for (int kt = 0; kt < K; kt += 32) {
    __syncthreads();
#pragma unroll
    for (int i = 0; i < 2; ++i) {
      int chunk = wid * 2 + i;
      int row = chunk * 16 + crow;
      const ushort* ga = A + (size_t)(m0 + row) * K + kt + ccol;
      const ushort* gb = B + (size_t)(n0 + row) * K + kt + ccol;
      __builtin_amdgcn_global_load_lds(
          (__attribute__((address_space(1))) void*)(void*)ga,
          (__attribute__((address_space(3))) void*)(&As[chunk * 512]), 16, 0, 0);
      __builtin_amdgcn_global_load_lds(
          (__attribute__((address_space(1))) void*)(void*)gb,
          (__attribute__((address_space(3))) void*)(&Bs[chunk * 512]), 16, 0, 0);
    }
    __syncthreads();

    bf16x8 af[4], bf[4];
#pragma unroll
    for (int m = 0; m < 4; ++m)
      af[m] = *reinterpret_cast<const bf16x8*>(&As[(wm + m * 16 + lr) * 32 + lg * 8]);
#pragma unroll
    for (int n = 0; n < 4; ++n)
      bf[n] = *reinterpret_cast<const bf16x8*>(&Bs[(wn + n * 16 + lr) * 32 + lg * 8]);
#pragma unroll
    for (int m = 0; m < 4; ++m)
#pragma unroll
      for (int n = 0; n < 4; ++n)
        acc[m][n] = __builtin_amdgcn_mfma_f32_16x16x32_bf16(af[m], bf[n], acc[m][n], 0, 0, 0);
  }

#pragma unroll
  for (int m = 0; m < 4; ++m) {
#pragma unroll
    for (int n = 0; n < 4; ++n) {
      int col = n0 + wn + n * 16 + lr;
      float bv = bias[col];
#pragma unroll
      for (int r = 0; r < 4; ++r) {
        int row = m0 + wm + m * 16 + lg * 4 + r;
        float v = acc[m][n][r] + bv;
        if (OUT_F32)
          ((float*)Cout)[(size_t)row * N + col] = v;
        else
          ((ushort*)Cout)[(size_t)row * N + col] = f2bf(v);
      }
    }
  }
}

// ---------------- RMSNorm(full 1536) + 3D RoPE, in place on bf16 ----------------
__global__ __launch_bounds__(256) void normrope(ushort* __restrict__ Qb,
                                                ushort* __restrict__ Kb,
                                                const float* __restrict__ gq,
                                                const float* __restrict__ gk,
                                                const float* __restrict__ cosT,
                                                const float* __restrict__ sinT) {
  __shared__ float red[4];
  const int l = blockIdx.x;
  const int tid = threadIdx.x;
  ushort* row = (blockIdx.y == 0 ? Qb : Kb) + (size_t)l * DIM;
  const float* g = blockIdx.y == 0 ? gq : gk;

  const uint* rp = reinterpret_cast<const uint*>(row);
  uint pk[3];
  float v[6];
#pragma unroll
  for (int i = 0; i < 3; ++i) {
    pk[i] = rp[tid * 3 + i];
    v[2 * i]     = bf2f((ushort)(pk[i] & 0xffff));
    v[2 * i + 1] = bf2f((ushort)(pk[i] >> 16));
  }
  float ss = 0.f;
#pragma unroll
  for (int i = 0; i < 6; ++i) ss += v[i] * v[i];
#pragma unroll
  for (int off = 1; off < 64; off <<= 1) ss += __shfl_xor(ss, off, 64);
  if ((tid & 63) == 0) red[tid >> 6] = ss;
  __syncthreads();
  float tot = red[0] + red[1] + red[2] + red[3];
  float rms = rsqrtf(tot * (1.0f / DIM) + 1e-6f);

  const int fi = l / 448;
  const int rem = l % 448;
  const int hi = rem / 28;
  const int wi = rem % 28;

  uint* wp = reinterpret_cast<uint*>(row);
#pragma unroll
  for (int i = 0; i < 3; ++i) {
    int p = tid * 3 + i;
    int head = p >> 6;
    int j = p & 63;
    int trow = (j < 22) ? fi : ((j < 43) ? hi : wi);
    float cv = cosT[trow * 64 + j];
    float sv = sinT[trow * 64 + j];
    int idx = head * 128 + 2 * j;
    float xr = v[2 * i] * rms * g[idx];
    float xi = v[2 * i + 1] * rms * g[idx + 1];
    float orr = xr * cv - xi * sv;
    float oii = xr * sv + xi * cv;
    wp[p] = (uint)f2bf(orr) | ((uint)f2bf(oii) << 16);
  }
}

// ---------------- flash attention: 4 waves x 32 q-rows, KVB=64, 32x32 MFMA ----
// Swapped QK^T: S^T = mfma(K_frag, Q_frag) -> col=lane&31=q, row=crow(r,hi)=k.
// KV-split (flash-decoding): grid.z = NSPLIT; each split covers a KV range and
// writes unnormalized f32 partials + (m,l); attn_merge combines. NSPLIT==1
// writes normalized bf16 directly.
#define QBLK 128
#define KVB  64

__global__ __launch_bounds__(256) void attn(const ushort* __restrict__ Q,
                                            const ushort* __restrict__ Kp,
                                            const ushort* __restrict__ Vp,
                                            ushort* __restrict__ O,
                                            float* __restrict__ Opart,
                                            float* __restrict__ mlbuf) {
  __shared__ __attribute__((aligned(16))) ushort Ks[KVB * 128];
  __shared__ __attribute__((aligned(16))) ushort Vt[128][72];   // V^T [d][k], padded
  __shared__ __attribute__((aligned(16))) ushort Ps[4][32][72]; // per-wave P [q][k], padded
  const int tid  = threadIdx.x;
  const int lane = tid & 63;
  const int wv   = tid >> 6;
  const int lq   = lane & 31;
  const int hi   = lane >> 5;
  const int h    = blockIdx.y;
  const int q0   = blockIdx.x * QBLK;
  const float scale = 0.08838834764831845f; // 1/sqrt(128)

  // KV range for this split
  const int split  = blockIdx.z;
  const int nsplit = gridDim.z;
  const int NT     = LSEQ / KVB;                 // 56 tiles
  const int t_lo   = split * NT / nsplit;
  const int t_hi   = (split + 1) * NT / nsplit;

  // Q fragments (B-operand): lane holds Q[q=lq][d = dstep*16 + hi*8 + j]
  bf16x8 qf[8];
  {
    const ushort* qbase = Q + (size_t)(q0 + wv * 32 + lq) * DIM + h * HD;
#pragma unroll
    for (int d = 0; d < 8; ++d)
      qf[d] = *reinterpret_cast<const bf16x8*>(qbase + d * 16 + hi * 8);
  }

  f32x16 accO[4] = {}; // [nd]: col d = nd*32+lq, row q = crow(r,hi)
  float m = -1e30f, lsum = 0.f;

  const int mbk = tid >> 4;  // 0..15 -> kv rows [4*mbk, +4)
  const int mbd = tid & 15;  // 0..15 -> d cols  [8*mbd, +8)

  for (int t = t_lo; t < t_hi; ++t) {
    const int kv0 = t * KVB;
    __syncthreads();
    // ---- K stage: swizzled source -> linear LDS, 4 issues/wave ----
#pragma unroll
    for (int i = 0; i < 4; ++i) {
      int o16 = (wv * 4 + i) * 64 + lane;        // 16B-unit index in tile
      int r = o16 >> 4;
      int b = (o16 & 15) * 16;                   // byte col within row
      int srcu = (b ^ ((r & 7) << 4)) >> 1;      // pre-swizzled ushort col
      const ushort* gp = Kp + (size_t)(kv0 + r) * DIM + h * HD + srcu;
      __builtin_amdgcn_global_load_lds(
          (__attribute__((address_space(1))) void*)(void*)gp,
          (__attribute__((address_space(3))) void*)(&Ks[(wv * 4 + i) * 512]), 16, 0, 0);
    }
    // ---- V stage: 4x8 micro-block transpose, b64 writes (bank-rotated) ----
    {
      const ushort* vbase = Vp + (size_t)(kv0 + mbk * 4) * DIM + h * HD + mbd * 8;
      uint4 r0 = *reinterpret_cast<const uint4*>(vbase);
      uint4 r1 = *reinterpret_cast<const uint4*>(vbase + DIM);
      uint4 r2 = *reinterpret_cast<const uint4*>(vbase + 2 * DIM);
      uint4 r3 = *reinterpret_cast<const uint4*>(vbase + 3 * DIM);
      const ushort* s0 = reinterpret_cast<const ushort*>(&r0);
      const ushort* s1 = reinterpret_cast<const ushort*>(&r1);
      const ushort* s2 = reinterpret_cast<const ushort*>(&r2);
      const ushort* s3 = reinterpret_cast<const ushort*>(&r3);
#pragma unroll
      for (int jj = 0; jj < 8; ++jj) {
        int j = (jj + mbd) & 7;  // rotate write order to spread banks
        uint2 w;
        w.x = (uint)s0[j] | ((uint)s1[j] << 16);
        w.y = (uint)s2[j] | ((uint)s3[j] << 16);
        *reinterpret_cast<uint2*>(&Vt[mbd * 8 + j][mbk * 4]) = w;
      }
    }
    __syncthreads();

    // ---- QK^T: S^T[k][q] in two 32-k halves ----
    f32x16 s0v = {}, s1v = {};
#pragma unroll
    for (int d = 0; d < 8; ++d) {
      int db = d * 32 + hi * 16;   // byte col of this lane's 16B A-chunk
      const bf16x8 a0 = *reinterpret_cast<const bf16x8*>(
          (const char*)Ks + lq * 256 + (db ^ ((lq & 7) << 4)));
      s0v = __builtin_amdgcn_mfma_f32_32x32x16_bf16(a0, qf[d], s0v, 0, 0, 0);
      const bf16x8 a1 = *reinterpret_cast<const bf16x8*>(
          (const char*)Ks + (32 + lq) * 256 + (db ^ ((lq & 7) << 4)));
      s1v = __builtin_amdgcn_mfma_f32_32x32x16_bf16(a1, qf[d], s1v, 0, 0, 0);
    }

    // ---- softmax (per-lane over 32 values; partner lane has other 32) ----
    float pmax = s0v[0];
#pragma unroll
    for (int r = 1; r < 16; ++r) pmax = fmaxf(pmax, s0v[r]);
#pragma unroll
    for (int r = 0; r < 16; ++r) pmax = fmaxf(pmax, s1v[r]);
    pmax = fmaxf(pmax, __shfl_xor(pmax, 32, 64));
    pmax *= scale;

    if (__any(pmax > m + 8.f)) {   // defer-max (T13)
      float mn = fmaxf(m, pmax);
      float al = __expf(m - mn);
      m = mn;
      lsum *= al;
#pragma unroll
      for (int r = 0; r < 16; ++r) {
        int qr = (r & 3) + 8 * (r >> 2) + 4 * hi;
        float alr = __shfl(al, qr, 64);
        accO[0][r] *= alr; accO[1][r] *= alr;
        accO[2][r] *= alr; accO[3][r] *= alr;
      }
    }

    float psum = 0.f;
#pragma unroll
    for (int ri = 0; ri < 4; ++ri) {
      {
        float p0 = __expf(fmaf(s0v[ri * 4 + 0], scale, -m));
        float p1 = __expf(fmaf(s0v[ri * 4 + 1], scale, -m));
        float p2 = __expf(fmaf(s0v[ri * 4 + 2], scale, -m));
        float p3 = __expf(fmaf(s0v[ri * 4 + 3], scale, -m));
        psum += (p0 + p1) + (p2 + p3);
        uint2 w; w.x = pkbf(p0, p1); w.y = pkbf(p2, p3);
        *reinterpret_cast<uint2*>(&Ps[wv][lq][8 * ri + 4 * hi]) = w;
      }
      {
        float p0 = __expf(fmaf(s1v[ri * 4 + 0], scale, -m));
        float p1 = __expf(fmaf(s1v[ri * 4 + 1], scale, -m));
        float p2 = __expf(fmaf(s1v[ri * 4 + 2], scale, -m));
        float p3 = __expf(fmaf(s1v[ri * 4 + 3], scale, -m));
        psum += (p0 + p1) + (p2 + p3);
        uint2 w; w.x = pkbf(p0, p1); w.y = pkbf(p2, p3);
        *reinterpret_cast<uint2*>(&Ps[wv][lq][32 + 8 * ri + 4 * hi]) = w;
      }
    }
    psum += __shfl_xor(psum, 32, 64);
    lsum += psum;

    // ---- PV: O += P @ V  (A = P from Ps, B = V^T from Vt) ----
#pragma unroll
    for (int ks = 0; ks < 4; ++ks) {
      bf16x8 pa = *reinterpret_cast<const bf16x8*>(&Ps[wv][lq][ks * 16 + hi * 8]);
#pragma unroll
      for (int nd = 0; nd < 4; ++nd) {
        bf16x8 vb = *reinterpret_cast<const bf16x8*>(&Vt[nd * 32 + lq][ks * 16 + hi * 8]);
        accO[nd] = __builtin_amdgcn_mfma_f32_32x32x16_bf16(pa, vb, accO[nd], 0, 0, 0);
      }
    }
  }

  // ---- epilogue ----
  if (gridDim.z == 1) {
    float inv_own = 1.0f / lsum;
#pragma unroll
    for (int r = 0; r < 16; ++r) {
      int qr = (r & 3) + 8 * (r >> 2) + 4 * hi;
      float inv = __shfl(inv_own, qr, 64);
      ushort* orow = O + (size_t)(q0 + wv * 32 + qr) * DIM + h * HD;
#pragma unroll
      for (int nd = 0; nd < 4; ++nd)
        orow[nd * 32 + lq] = f2bf(accO[nd][r] * inv);
    }
  } else {
    // unnormalized partials: Opart[split][h][q][d], ml[split][h*LSEQ+q] = {m,l}
    float* Op = Opart + ((size_t)split * HEADS + h) * ((size_t)LSEQ * HD);
#pragma unroll
    for (int r = 0; r < 16; ++r) {
      int qr = (r & 3) + 8 * (r >> 2) + 4 * hi;
      float* orow = Op + (size_t)(q0 + wv * 32 + qr) * HD;
#pragma unroll
      for (int nd = 0; nd < 4; ++nd)
        orow[nd * 32 + lq] = accO[nd][r];
    }
    if (hi == 0) {
      size_t row = (size_t)split * (HEADS * LSEQ) + (size_t)h * LSEQ + (q0 + wv * 32 + lq);
      mlbuf[2 * row]     = m;
      mlbuf[2 * row + 1] = lsum;
    }
  }
}

// ---------------- merge of KV-split partials ----------------
__global__ __launch_bounds__(256) void attn_merge(const float* __restrict__ Opart,
                                                  const float* __restrict__ mlbuf,
                                                  ushort* __restrict__ Ob, int nsplit) {
  const int RN = HEADS * LSEQ;          // rows per split
  int gi = blockIdx.x * 256 + threadIdx.x;   // one float4 of one (h,q) row
  int row = gi >> 5;                    // h*LSEQ + q
  int d4 = (gi & 31) * 4;
  if (row >= RN) return;
  int h = row / LSEQ, q = row % LSEQ;

  float M = -1e30f;
  for (int s = 0; s < nsplit; ++s) M = fmaxf(M, mlbuf[2 * ((size_t)s * RN + row)]);
  float den = 0.f;
  float4 acc = {0.f, 0.f, 0.f, 0.f};
  for (int s = 0; s < nsplit; ++s) {
    float ms = mlbuf[2 * ((size_t)s * RN + row)];
    float ls = mlbuf[2 * ((size_t)s * RN + row) + 1];
    float w = __expf(ms - M);
    den += ls * w;
    const float4 o = *reinterpret_cast<const float4*>(
        &Opart[((size_t)s * RN + row) * HD + d4]);
    acc.x += w * o.x; acc.y += w * o.y; acc.z += w * o.z; acc.w += w * o.w;
  }
  float inv = 1.0f / den;
  ushort4 r;
  r.x = f2bf(acc.x * inv); r.y = f2bf(acc.y * inv);
  r.z = f2bf(acc.z * inv); r.w = f2bf(acc.w * inv);
  *reinterpret_cast<ushort4*>(&Ob[(size_t)q * DIM + h * HD + d4]) = r;
}

// ---------------- launch ----------------
extern "C" void kernel_launch(void* const* d_in, const int* in_sizes, int n_in,
                              void* d_out, int out_size, void* d_ws, size_t ws_size,
                              hipStream_t stream) {
  (void)in_sizes; (void)n_in; (void)out_size;
  const float* x    = (const float*)d_in[0];
  const float* cosT = (const float*)d_in[1];
  const float* sinT = (const float*)d_in[2];
  const float* Wq   = (const float*)d_in[3];
  const float* bq   = (const float*)d_in[4];
  const float* Wk   = (const float*)d_in[5];
  const float* bk   = (const float*)d_in[6];
  const float* Wv   = (const float*)d_in[7];
  const float* bv   = (const float*)d_in[8];
  const float* Wo   = (const float*)d_in[9];
  const float* bo   = (const float*)d_in[10];
  const float* gq   = (const float*)d_in[11];
  const float* gk   = (const float*)d_in[12];

  const size_t LD = (size_t)LSEQ * DIM;
  const size_t WD = (size_t)DIM * DIM;
  const size_t base_bytes = (5 * LD + 4 * WD) * sizeof(ushort);
  if (ws_size < base_bytes) return;

  ushort* xb  = (ushort*)d_ws;
  ushort* Wqb = xb + LD;
  ushort* Wkb = Wqb + WD;
  ushort* Wvb = Wkb + WD;
  ushort* Wob = Wvb + WD;
  ushort* Qb  = Wob + WD;
  ushort* Kb  = Qb + LD;
  ushort* Vb  = Kb + LD;
  ushort* Ob  = Vb + LD;

  // KV-split sizing from available workspace (deterministic in ws_size)
  const size_t RN = (size_t)HEADS * LSEQ;              // 43008 rows
  const size_t split_bytes = RN * HD * 4 + RN * 8;     // O partial + (m,l)
  int nsplit = 1;
  if (ws_size >= base_bytes + 3 * split_bytes) nsplit = 3;
  else if (ws_size >= base_bytes + 2 * split_bytes) nsplit = 2;
  float* Opart = (float*)((char*)d_ws + base_bytes);
  float* mlbuf = Opart + (size_t)nsplit * RN * HD;

  cvt_f32_bf16<<<(int)(LD / 4 / 256), 256, 0, stream>>>(x, xb, (int)LD);
  cvt_f32_bf16<<<(int)(WD / 4 / 256), 256, 0, stream>>>(Wq, Wqb, (int)WD);
  cvt_f32_bf16<<<(int)(WD / 4 / 256), 256, 0, stream>>>(Wk, Wkb, (int)WD);
  cvt_f32_bf16<<<(int)(WD / 4 / 256), 256, 0, stream>>>(Wv, Wvb, (int)WD);
  cvt_f32_bf16<<<(int)(WD / 4 / 256), 256, 0, stream>>>(Wo, Wob, (int)WD);

  dim3 ggrid(LSEQ / 128, DIM / 128);
  gemm_bt<false><<<ggrid, 256, 0, stream>>>(xb, Wqb, bq, Qb, LSEQ, DIM, DIM);
  gemm_bt<false><<<ggrid, 256, 0, stream>>>(xb, Wkb, bk, Kb, LSEQ, DIM, DIM);
  gemm_bt<false><<<ggrid, 256, 0, stream>>>(xb, Wvb, bv, Vb, LSEQ, DIM, DIM);

  normrope<<<dim3(LSEQ, 2), 256, 0, stream>>>(Qb, Kb, gq, gk, cosT, sinT);

  attn<<<dim3(LSEQ / QBLK, HEADS, nsplit), 256, 0, stream>>>(Qb, Kb, Vb, Ob, Opart, mlbuf);
  if (nsplit > 1)
    attn_merge<<<(int)(RN * 32 / 256), 256, 0, stream>>>(Opart, mlbuf, Ob, nsplit);

  gemm_bt<true><<<ggrid, 256, 0, stream>>>(Ob, Wob, bo, d_out, LSEQ, DIM, DIM);
}

// Round 6
// 368.566 us; speedup vs baseline: 1.6520x; 1.3511x over previous
//
#include <hip/hip_runtime.h>
#include <hip/hip_bf16.h>

// WanSelfAttention: x[1,3584,1536] -> QKV proj -> RMSNorm(full dim) -> 3D RoPE
// -> 12-head attention (HD=128) -> out proj. All matmuls bf16 MFMA, f32 accum.

#define DIM   1536
#define HEADS 12
#define HD    128
#define LSEQ  3584

typedef __bf16 bf16_t;
typedef __attribute__((ext_vector_type(8))) __bf16 bf16x8;
typedef __attribute__((ext_vector_type(4))) float f32x4;
typedef __attribute__((ext_vector_type(16))) float f32x16;

static __device__ __forceinline__ ushort f2bf(float f) {
  bf16_t h = (bf16_t)f;
  return __builtin_bit_cast(ushort, h);
}
static __device__ __forceinline__ float bf2f(ushort u) {
  return (float)__builtin_bit_cast(bf16_t, u);
}
static __device__ __forceinline__ uint pkbf(float a, float b) {
  return (uint)f2bf(a) | ((uint)f2bf(b) << 16);
}

// ---------------- f32 -> bf16 convert ----------------
__global__ __launch_bounds__(256) void cvt_f32_bf16(const float* __restrict__ in,
                                                    ushort* __restrict__ out, int n) {
  int i = (blockIdx.x * 256 + threadIdx.x) * 4;
  if (i + 3 < n) {
    float4 v = *reinterpret_cast<const float4*>(in + i);
    ushort4 o;
    o.x = f2bf(v.x); o.y = f2bf(v.y); o.z = f2bf(v.z); o.w = f2bf(v.w);
    *reinterpret_cast<ushort4*>(out + i) = o;
  }
}

// ---------------- GEMM: C[M][N] = A[M][K] @ B[N][K]^T + bias ----------------
template <bool OUT_F32>
__global__ __launch_bounds__(256) void gemm_bt(const ushort* __restrict__ A,
                                               const ushort* __restrict__ B,
                                               const float* __restrict__ bias,
                                               void* __restrict__ Cout,
                                               int M, int N, int K) {
  __shared__ __attribute__((aligned(16))) ushort As[128 * 32];
  __shared__ __attribute__((aligned(16))) ushort Bs[128 * 32];
  const int tid  = threadIdx.x;
  const int lane = tid & 63;
  const int wid  = tid >> 6;
  const int m0 = blockIdx.x * 128;
  const int n0 = blockIdx.y * 128;
  const int wm = (wid >> 1) * 64;
  const int wn = (wid & 1) * 64;
  const int lr = lane & 15;
  const int lg = lane >> 4;
  const int crow = lane >> 2;
  const int ccol = (lane & 3) * 8;

  f32x4 acc[4][4] = {};

  for (int kt = 0; kt < K; kt += 32) {
    __syncthreads();
#pragma unroll
    for (int i = 0; i < 2; ++i) {
      int chunk = wid * 2 + i;
      int row = chunk * 16 + crow;
      const ushort* ga = A + (size_t)(m0 + row) * K + kt + ccol;
      const ushort* gb = B + (size_t)(n0 + row) * K + kt + ccol;
      __builtin_amdgcn_global_load_lds(
          (__attribute__((address_space(1))) void*)(void*)ga,
          (__attribute__((address_space(3))) void*)(&As[chunk * 512]), 16, 0, 0);
      __builtin_amdgcn_global_load_lds(
          (__attribute__((address_space(1))) void*)(void*)gb,
          (__attribute__((address_space(3))) void*)(&Bs[chunk * 512]), 16, 0, 0);
    }
    __syncthreads();

    bf16x8 af[4], bf[4];
#pragma unroll
    for (int m = 0; m < 4; ++m)
      af[m] = *reinterpret_cast<const bf16x8*>(&As[(wm + m * 16 + lr) * 32 + lg * 8]);
#pragma unroll
    for (int n = 0; n < 4; ++n)
      bf[n] = *reinterpret_cast<const bf16x8*>(&Bs[(wn + n * 16 + lr) * 32 + lg * 8]);
#pragma unroll
    for (int m = 0; m < 4; ++m)
#pragma unroll
      for (int n = 0; n < 4; ++n)
        acc[m][n] = __builtin_amdgcn_mfma_f32_16x16x32_bf16(af[m], bf[n], acc[m][n], 0, 0, 0);
  }

#pragma unroll
  for (int m = 0; m < 4; ++m) {
#pragma unroll
    for (int n = 0; n < 4; ++n) {
      int col = n0 + wn + n * 16 + lr;
      float bv = bias[col];
#pragma unroll
      for (int r = 0; r < 4; ++r) {
        int row = m0 + wm + m * 16 + lg * 4 + r;
        float v = acc[m][n][r] + bv;
        if (OUT_F32)
          ((float*)Cout)[(size_t)row * N + col] = v;
        else
          ((ushort*)Cout)[(size_t)row * N + col] = f2bf(v);
      }
    }
  }
}

// ---------------- RMSNorm(full 1536) + 3D RoPE, in place on bf16 ----------------
__global__ __launch_bounds__(256) void normrope(ushort* __restrict__ Qb,
                                                ushort* __restrict__ Kb,
                                                const float* __restrict__ gq,
                                                const float* __restrict__ gk,
                                                const float* __restrict__ cosT,
                                                const float* __restrict__ sinT) {
  __shared__ float red[4];
  const int l = blockIdx.x;
  const int tid = threadIdx.x;
  ushort* row = (blockIdx.y == 0 ? Qb : Kb) + (size_t)l * DIM;
  const float* g = blockIdx.y == 0 ? gq : gk;

  const uint* rp = reinterpret_cast<const uint*>(row);
  uint pk[3];
  float v[6];
#pragma unroll
  for (int i = 0; i < 3; ++i) {
    pk[i] = rp[tid * 3 + i];
    v[2 * i]     = bf2f((ushort)(pk[i] & 0xffff));
    v[2 * i + 1] = bf2f((ushort)(pk[i] >> 16));
  }
  float ss = 0.f;
#pragma unroll
  for (int i = 0; i < 6; ++i) ss += v[i] * v[i];
#pragma unroll
  for (int off = 1; off < 64; off <<= 1) ss += __shfl_xor(ss, off, 64);
  if ((tid & 63) == 0) red[tid >> 6] = ss;
  __syncthreads();
  float tot = red[0] + red[1] + red[2] + red[3];
  float rms = rsqrtf(tot * (1.0f / DIM) + 1e-6f);

  const int fi = l / 448;
  const int rem = l % 448;
  const int hi = rem / 28;
  const int wi = rem % 28;

  uint* wp = reinterpret_cast<uint*>(row);
#pragma unroll
  for (int i = 0; i < 3; ++i) {
    int p = tid * 3 + i;
    int head = p >> 6;
    int j = p & 63;
    int trow = (j < 22) ? fi : ((j < 43) ? hi : wi);
    float cv = cosT[trow * 64 + j];
    float sv = sinT[trow * 64 + j];
    int idx = head * 128 + 2 * j;
    float xr = v[2 * i] * rms * g[idx];
    float xi = v[2 * i + 1] * rms * g[idx + 1];
    float orr = xr * cv - xi * sv;
    float oii = xr * sv + xi * cv;
    wp[p] = (uint)f2bf(orr) | ((uint)f2bf(oii) << 16);
  }
}

// ---------------- flash attention: 4 waves x 32 q-rows, KVB=64 staged,
// processed as two sequential 32-k online-softmax subtiles (reg pressure!).
// Swapped QK^T: S^T = mfma(K_frag, Q_frag) -> col=lane&31=q, row=crow(r,hi)=k.
// KV-split across grid.z; partials merged by attn_merge.
#define QBLK 128
#define KVB  64

__global__ __launch_bounds__(256, 2) void attn(const ushort* __restrict__ Q,
                                               const ushort* __restrict__ Kp,
                                               const ushort* __restrict__ Vp,
                                               ushort* __restrict__ O,
                                               float* __restrict__ Opart,
                                               float* __restrict__ mlbuf) {
  __shared__ __attribute__((aligned(16))) ushort Ks[KVB * 128];
  __shared__ __attribute__((aligned(16))) ushort Vt[128][72];   // V^T [d][k], padded
  __shared__ __attribute__((aligned(16))) ushort Ps[4][32][40]; // per-wave P [q][k<32], padded
  const int tid  = threadIdx.x;
  const int lane = tid & 63;
  const int wv   = tid >> 6;
  const int lq   = lane & 31;
  const int hi   = lane >> 5;
  const int h    = blockIdx.y;
  const int q0   = blockIdx.x * QBLK;
  const float scale = 0.08838834764831845f; // 1/sqrt(128)

  const int split  = blockIdx.z;
  const int nsplit = gridDim.z;
  const int NT     = LSEQ / KVB;                 // 56 tiles
  const int t_lo   = split * NT / nsplit;
  const int t_hi   = (split + 1) * NT / nsplit;

  // Q fragments (B-operand): lane holds Q[q=lq][d = dstep*16 + hi*8 + j]
  bf16x8 qf[8];
  {
    const ushort* qbase = Q + (size_t)(q0 + wv * 32 + lq) * DIM + h * HD;
#pragma unroll
    for (int d = 0; d < 8; ++d)
      qf[d] = *reinterpret_cast<const bf16x8*>(qbase + d * 16 + hi * 8);
  }

  f32x16 accO[4] = {}; // [nd]: col d = nd*32+lq, row q = crow(r,hi)
  float m = -1e30f, lsum = 0.f;

  const int mbk = tid >> 4;  // 0..15 -> kv rows [4*mbk, +4)
  const int mbd = tid & 15;  // 0..15 -> d cols  [8*mbd, +8)

  for (int t = t_lo; t < t_hi; ++t) {
    const int kv0 = t * KVB;
    __syncthreads();
    // ---- K stage: swizzled source -> linear LDS, 4 issues/wave ----
#pragma unroll
    for (int i = 0; i < 4; ++i) {
      int o16 = (wv * 4 + i) * 64 + lane;        // 16B-unit index in tile
      int r = o16 >> 4;
      int b = (o16 & 15) * 16;                   // byte col within row
      int srcu = (b ^ ((r & 7) << 4)) >> 1;      // pre-swizzled ushort col
      const ushort* gp = Kp + (size_t)(kv0 + r) * DIM + h * HD + srcu;
      __builtin_amdgcn_global_load_lds(
          (__attribute__((address_space(1))) void*)(void*)gp,
          (__attribute__((address_space(3))) void*)(&Ks[(wv * 4 + i) * 512]), 16, 0, 0);
    }
    // ---- V stage: 4x8 micro-block transpose, b64 writes (bank-rotated) ----
    {
      const ushort* vbase = Vp + (size_t)(kv0 + mbk * 4) * DIM + h * HD + mbd * 8;
      uint4 r0 = *reinterpret_cast<const uint4*>(vbase);
      uint4 r1 = *reinterpret_cast<const uint4*>(vbase + DIM);
      uint4 r2 = *reinterpret_cast<const uint4*>(vbase + 2 * DIM);
      uint4 r3 = *reinterpret_cast<const uint4*>(vbase + 3 * DIM);
      const ushort* s0 = reinterpret_cast<const ushort*>(&r0);
      const ushort* s1 = reinterpret_cast<const ushort*>(&r1);
      const ushort* s2 = reinterpret_cast<const ushort*>(&r2);
      const ushort* s3 = reinterpret_cast<const ushort*>(&r3);
#pragma unroll
      for (int jj = 0; jj < 8; ++jj) {
        int j = (jj + mbd) & 7;  // rotate write order to spread banks
        uint2 w;
        w.x = (uint)s0[j] | ((uint)s1[j] << 16);
        w.y = (uint)s2[j] | ((uint)s3[j] << 16);
        *reinterpret_cast<uint2*>(&Vt[mbd * 8 + j][mbk * 4]) = w;
      }
    }
    __syncthreads();

    // ---- two sequential 32-k subtiles (keeps only ONE f32x16 S live) ----
#pragma unroll
    for (int hf = 0; hf < 2; ++hf) {
      f32x16 sv = {};
#pragma unroll
      for (int d = 0; d < 8; ++d) {
        int db = d * 32 + hi * 16;   // byte col of this lane's 16B A-chunk
        const bf16x8 a = *reinterpret_cast<const bf16x8*>(
            (const char*)Ks + (hf * 32 + lq) * 256 + (db ^ ((lq & 7) << 4)));
        sv = __builtin_amdgcn_mfma_f32_32x32x16_bf16(a, qf[d], sv, 0, 0, 0);
      }

      // softmax over this 32-k subtile (lane owns q-row; partner has other 16 k)
      float pmax = sv[0];
#pragma unroll
      for (int r = 1; r < 16; ++r) pmax = fmaxf(pmax, sv[r]);
      pmax = fmaxf(pmax, __shfl_xor(pmax, 32, 64));
      pmax *= scale;

      if (__any(pmax > m + 8.f)) {   // defer-max (T13)
        float mn = fmaxf(m, pmax);
        float al = __expf(m - mn);
        m = mn;
        lsum *= al;
#pragma unroll
        for (int r = 0; r < 16; ++r) {
          int qr = (r & 3) + 8 * (r >> 2) + 4 * hi;
          float alr = __shfl(al, qr, 64);
          accO[0][r] *= alr; accO[1][r] *= alr;
          accO[2][r] *= alr; accO[3][r] *= alr;
        }
      }

      float psum = 0.f;
#pragma unroll
      for (int ri = 0; ri < 4; ++ri) {
        float p0 = __expf(fmaf(sv[ri * 4 + 0], scale, -m));
        float p1 = __expf(fmaf(sv[ri * 4 + 1], scale, -m));
        float p2 = __expf(fmaf(sv[ri * 4 + 2], scale, -m));
        float p3 = __expf(fmaf(sv[ri * 4 + 3], scale, -m));
        psum += (p0 + p1) + (p2 + p3);
        uint2 w; w.x = pkbf(p0, p1); w.y = pkbf(p2, p3);
        *reinterpret_cast<uint2*>(&Ps[wv][lq][8 * ri + 4 * hi]) = w;
      }
      psum += __shfl_xor(psum, 32, 64);
      lsum += psum;

      // ---- PV over this 32-k subtile (per-wave Ps: no barrier needed) ----
#pragma unroll
      for (int ks = 0; ks < 2; ++ks) {
        bf16x8 pa = *reinterpret_cast<const bf16x8*>(&Ps[wv][lq][ks * 16 + hi * 8]);
#pragma unroll
        for (int nd = 0; nd < 4; ++nd) {
          bf16x8 vb = *reinterpret_cast<const bf16x8*>(
              &Vt[nd * 32 + lq][hf * 32 + ks * 16 + hi * 8]);
          accO[nd] = __builtin_amdgcn_mfma_f32_32x32x16_bf16(pa, vb, accO[nd], 0, 0, 0);
        }
      }
    }
  }

  // ---- epilogue ----
  if (gridDim.z == 1) {
    float inv_own = 1.0f / lsum;
#pragma unroll
    for (int r = 0; r < 16; ++r) {
      int qr = (r & 3) + 8 * (r >> 2) + 4 * hi;
      float inv = __shfl(inv_own, qr, 64);
      ushort* orow = O + (size_t)(q0 + wv * 32 + qr) * DIM + h * HD;
#pragma unroll
      for (int nd = 0; nd < 4; ++nd)
        orow[nd * 32 + lq] = f2bf(accO[nd][r] * inv);
    }
  } else {
    // unnormalized partials: Opart[split][h][q][d], ml[split][h*LSEQ+q] = {m,l}
    float* Op = Opart + ((size_t)split * HEADS + h) * ((size_t)LSEQ * HD);
#pragma unroll
    for (int r = 0; r < 16; ++r) {
      int qr = (r & 3) + 8 * (r >> 2) + 4 * hi;
      float* orow = Op + (size_t)(q0 + wv * 32 + qr) * HD;
#pragma unroll
      for (int nd = 0; nd < 4; ++nd)
        orow[nd * 32 + lq] = accO[nd][r];
    }
    if (hi == 0) {
      size_t row = (size_t)split * (HEADS * LSEQ) + (size_t)h * LSEQ + (q0 + wv * 32 + lq);
      mlbuf[2 * row]     = m;
      mlbuf[2 * row + 1] = lsum;
    }
  }
}

// ---------------- merge of KV-split partials ----------------
__global__ __launch_bounds__(256) void attn_merge(const float* __restrict__ Opart,
                                                  const float* __restrict__ mlbuf,
                                                  ushort* __restrict__ Ob, int nsplit) {
  const int RN = HEADS * LSEQ;          // rows per split
  int gi = blockIdx.x * 256 + threadIdx.x;   // one float4 of one (h,q) row
  int row = gi >> 5;                    // h*LSEQ + q
  int d4 = (gi & 31) * 4;
  if (row >= RN) return;
  int h = row / LSEQ, q = row % LSEQ;

  float M = -1e30f;
  for (int s = 0; s < nsplit; ++s) M = fmaxf(M, mlbuf[2 * ((size_t)s * RN + row)]);
  float den = 0.f;
  float4 acc = {0.f, 0.f, 0.f, 0.f};
  for (int s = 0; s < nsplit; ++s) {
    float ms = mlbuf[2 * ((size_t)s * RN + row)];
    float ls = mlbuf[2 * ((size_t)s * RN + row) + 1];
    float w = __expf(ms - M);
    den += ls * w;
    const float4 o = *reinterpret_cast<const float4*>(
        &Opart[((size_t)s * RN + row) * HD + d4]);
    acc.x += w * o.x; acc.y += w * o.y; acc.z += w * o.z; acc.w += w * o.w;
  }
  float inv = 1.0f / den;
  ushort4 r;
  r.x = f2bf(acc.x * inv); r.y = f2bf(acc.y * inv);
  r.z = f2bf(acc.z * inv); r.w = f2bf(acc.w * inv);
  *reinterpret_cast<ushort4*>(&Ob[(size_t)q * DIM + h * HD + d4]) = r;
}

// ---------------- launch ----------------
extern "C" void kernel_launch(void* const* d_in, const int* in_sizes, int n_in,
                              void* d_out, int out_size, void* d_ws, size_t ws_size,
                              hipStream_t stream) {
  (void)in_sizes; (void)n_in; (void)out_size;
  const float* x    = (const float*)d_in[0];
  const float* cosT = (const float*)d_in[1];
  const float* sinT = (const float*)d_in[2];
  const float* Wq   = (const float*)d_in[3];
  const float* bq   = (const float*)d_in[4];
  const float* Wk   = (const float*)d_in[5];
  const float* bk   = (const float*)d_in[6];
  const float* Wv   = (const float*)d_in[7];
  const float* bv   = (const float*)d_in[8];
  const float* Wo   = (const float*)d_in[9];
  const float* bo   = (const float*)d_in[10];
  const float* gq   = (const float*)d_in[11];
  const float* gk   = (const float*)d_in[12];

  const size_t LD = (size_t)LSEQ * DIM;
  const size_t WD = (size_t)DIM * DIM;
  const size_t base_bytes = (5 * LD + 4 * WD) * sizeof(ushort);
  if (ws_size < base_bytes) return;

  ushort* xb  = (ushort*)d_ws;
  ushort* Wqb = xb + LD;
  ushort* Wkb = Wqb + WD;
  ushort* Wvb = Wkb + WD;
  ushort* Wob = Wvb + WD;
  ushort* Qb  = Wob + WD;
  ushort* Kb  = Qb + LD;
  ushort* Vb  = Kb + LD;
  ushort* Ob  = Vb + LD;

  // KV-split sizing from available workspace (deterministic in ws_size)
  const size_t RN = (size_t)HEADS * LSEQ;              // 43008 rows
  const size_t split_bytes = RN * HD * 4 + RN * 8;     // O partial + (m,l)
  int nsplit = 1;
  if (ws_size >= base_bytes + 3 * split_bytes) nsplit = 3;
  else if (ws_size >= base_bytes + 2 * split_bytes) nsplit = 2;
  float* Opart = (float*)((char*)d_ws + base_bytes);
  float* mlbuf = Opart + (size_t)nsplit * RN * HD;

  cvt_f32_bf16<<<(int)(LD / 4 / 256), 256, 0, stream>>>(x, xb, (int)LD);
  cvt_f32_bf16<<<(int)(WD / 4 / 256), 256, 0, stream>>>(Wq, Wqb, (int)WD);
  cvt_f32_bf16<<<(int)(WD / 4 / 256), 256, 0, stream>>>(Wk, Wkb, (int)WD);
  cvt_f32_bf16<<<(int)(WD / 4 / 256), 256, 0, stream>>>(Wv, Wvb, (int)WD);
  cvt_f32_bf16<<<(int)(WD / 4 / 256), 256, 0, stream>>>(Wo, Wob, (int)WD);

  dim3 ggrid(LSEQ / 128, DIM / 128);
  gemm_bt<false><<<ggrid, 256, 0, stream>>>(xb, Wqb, bq, Qb, LSEQ, DIM, DIM);
  gemm_bt<false><<<ggrid, 256, 0, stream>>>(xb, Wkb, bk, Kb, LSEQ, DIM, DIM);
  gemm_bt<false><<<ggrid, 256, 0, stream>>>(xb, Wvb, bv, Vb, LSEQ, DIM, DIM);

  normrope<<<dim3(LSEQ, 2), 256, 0, stream>>>(Qb, Kb, gq, gk, cosT, sinT);

  attn<<<dim3(LSEQ / QBLK, HEADS, nsplit), 256, 0, stream>>>(Qb, Kb, Vb, Ob, Opart, mlbuf);
  if (nsplit > 1)
    attn_merge<<<(int)(RN * 32 / 256), 256, 0, stream>>>(Opart, mlbuf, Ob, nsplit);

  gemm_bt<true><<<ggrid, 256, 0, stream>>>(Ob, Wob, bo, d_out, LSEQ, DIM, DIM);
}